// Round 10
// baseline (153.424 us; speedup 1.0000x reference)
//
#include <hip/hip_runtime.h>
#include <stdint.h>

typedef float  f32x4  __attribute__((ext_vector_type(4)));
typedef __bf16 bf16x8 __attribute__((ext_vector_type(8)));
typedef __bf16 bf16x4 __attribute__((ext_vector_type(4)));

#define N_ 256
#define C_ 512
#define H_ 64
#define RS_ 32768  // row stride in transposed tensors: H_*C_ elements

__device__ __forceinline__ uint32_t pack_bf16x2(float a, float b) {
  const uint16_t ua = __builtin_bit_cast(uint16_t, (__bf16)a);
  const uint16_t ub = __builtin_bit_cast(uint16_t, (__bf16)b);
  return (uint32_t)ua | ((uint32_t)ub << 16);
}

// ---------------------------------------------------------------------------
// LDS-free direct transpose: (P,512c,64h) fp32 -> (P,64h,512c) bf16.
// Thread = (p, h=lane, c-octet): 8 wave-loads of 256B contiguous (lanes sweep
// h at fixed c -- native layout is h-innermost), pack bf16x8 in-register,
// ONE 16B store at dst[p][lane][c0].  A block's 4 waves take c-offsets
// {0,8,16,24} of a 32c range = exactly one 64B line per h-row, so store
// merging is INTRA-block on one L2 (R9's failure was cross-XCD merge).
// Zero LDS, zero barriers, ~24 VGPR -> 32 waves/CU, 8+ loads in flight/wave
// (Little's law: ~64KB/CU outstanding -> BW-bound, not latency-bound).
// task = (p, 32c-block): 20480 tasks, grid 2048, 10 per block.
// Block 0 zeroes BN stats.
// ---------------------------------------------------------------------------
__global__ __launch_bounds__(256) void k_prep_direct(
    const float* __restrict__ x, const float* __restrict__ w1,
    const float* __restrict__ w2,
    __bf16* __restrict__ xT, __bf16* __restrict__ w1T,
    __bf16* __restrict__ w2T, float* __restrict__ stats) {
  const int t = threadIdx.x;
  if (blockIdx.x == 0) {
#pragma unroll
    for (int i = 0; i < 8; ++i) stats[i * 256 + t] = 0.f;  // sum1,sq1,sum2,sq2
  }
  const int wv = t >> 6, l = t & 63;
#pragma unroll 2
  for (int task = blockIdx.x; task < 20480; task += 2048) {
    const int p  = task >> 4;                 // 0..1279
    const int c0 = (task & 15) * 32 + wv * 8; // wave's c-octet
    const float* src;
    __bf16* dst;
    int pp;
    if (p < 256)      { src = x;  dst = xT;  pp = p; }
    else if (p < 768) { src = w1; dst = w1T; pp = p - 256; }
    else              { src = w2; dst = w2T; pp = p - 768; }
    const float* S = src + (size_t)pp * 32768 + (size_t)c0 * 64 + l;
    float v[8];
#pragma unroll
    for (int j = 0; j < 8; ++j) v[j] = S[j * 64];
    uint4 o;
    o.x = pack_bf16x2(v[0], v[1]);
    o.y = pack_bf16x2(v[2], v[3]);
    o.z = pack_bf16x2(v[4], v[5]);
    o.w = pack_bf16x2(v[6], v[7]);
    *reinterpret_cast<uint4*>(dst + (size_t)pp * RS_ + (size_t)l * 512 + c0) = o;
  }
}

// ---------------------------------------------------------------------------
// Batched NT GEMM body: per h, C[256][512] = A[256][512]*B[512][512]^T (bf16)
// Layouts (row stride RS_). 128x128 tile, 4 waves, BK=64, double-buffered
// global_load_lds staging with chunk-XOR swizzle via pre-swizzled source.
// gblk in [0,512): wkid = (gblk&7)*64 + (gblk>>3) colocates same-h on XCD.
// Epilogue: bf16 C + per-channel sum/sumsq atomics.
// BN_A: A gets y = relu(a1[k]*a + c1[k]) from sum_in/sq_in on the fly.
// ---------------------------------------------------------------------------
template <bool BN_A>
__device__ __forceinline__ void gemm_body(
    const __bf16* __restrict__ A, const __bf16* __restrict__ B,
    __bf16* __restrict__ Co,
    const float* __restrict__ sum_in, const float* __restrict__ sq_in,
    const float* __restrict__ g, const float* __restrict__ bb,
    float* __restrict__ sum_out, float* __restrict__ sq_out,
    int gblk, int tid, __bf16* AsB, __bf16* BsB,
    float* a_lds, float* c_lds) {
  const int wkid = (gblk & 7) * 64 + (gblk >> 3);
  const int h  = wkid >> 3;
  const int tm = (wkid >> 2) & 1, tn = wkid & 3;
  const int m0 = tm * 128, n0 = tn * 128;
  const __bf16* Ah = A + (size_t)m0 * RS_ + (size_t)h * C_;
  const __bf16* Bh = B + (size_t)n0 * RS_ + (size_t)h * C_;
  const int lane = tid & 63, wid = tid >> 6;
  const int wr = wid >> 1, wc = wid & 1;
  const int lrow8 = lane >> 3;
  const int swz   = (lane & 7) ^ lrow8;

  if (BN_A) {
#pragma unroll
    for (int ch = tid; ch < 512; ch += 256) {
      const float m    = sum_in[ch] * (1.f / 16384.f);
      const float var  = fmaxf(0.f, sq_in[ch] * (1.f / 16384.f) - m * m);
      const float aa   = g[ch] * rsqrtf(var + 1e-5f);
      a_lds[ch] = aa;
      c_lds[ch] = bb[ch] - m * aa;
    }
    __syncthreads();
  }

  auto stage_b = [&](int buf, int kt) {
#pragma unroll
    for (int i = 0; i < 4; ++i) {
      const int rbase = wid * 32 + i * 8;
      const __bf16* gb = Bh + (size_t)(rbase + lrow8) * RS_ + kt * 64 + swz * 8;
      __builtin_amdgcn_global_load_lds(
          (const __attribute__((address_space(1))) void*)gb,
          (__attribute__((address_space(3))) void*)(BsB + buf * 8192 + rbase * 64),
          16, 0, 0);
    }
  };
  auto stage_a = [&](int buf, int kt) {
#pragma unroll
    for (int i = 0; i < 4; ++i) {
      const int rbase = wid * 32 + i * 8;
      const __bf16* ga = Ah + (size_t)(rbase + lrow8) * RS_ + kt * 64 + swz * 8;
      __builtin_amdgcn_global_load_lds(
          (const __attribute__((address_space(1))) void*)ga,
          (__attribute__((address_space(3))) void*)(AsB + buf * 8192 + rbase * 64),
          16, 0, 0);
    }
  };
  const int lr32 = tid >> 3, cch = tid & 7;
  auto load_a = [&](bf16x8* v, int kt) {
#pragma unroll
    for (int i = 0; i < 4; ++i)
      v[i] = *reinterpret_cast<const bf16x8*>(
          Ah + (size_t)(i * 32 + lr32) * RS_ + kt * 64 + cch * 8);
  };
  auto bn_write = [&](const bf16x8* v, int buf, int kt) {
    const int cg = kt * 64 + cch * 8;
    const f32x4 s0 = *reinterpret_cast<const f32x4*>(&a_lds[cg]);
    const f32x4 s1 = *reinterpret_cast<const f32x4*>(&a_lds[cg + 4]);
    const f32x4 h0 = *reinterpret_cast<const f32x4*>(&c_lds[cg]);
    const f32x4 h1 = *reinterpret_cast<const f32x4*>(&c_lds[cg + 4]);
#pragma unroll
    for (int i = 0; i < 4; ++i) {
      const int row = i * 32 + lr32;
      bf16x8 y;
#pragma unroll
      for (int e = 0; e < 4; ++e) {
        y[e]     = (__bf16)fmaxf(0.f, fmaf((float)v[i][e],     s0[e], h0[e]));
        y[e + 4] = (__bf16)fmaxf(0.f, fmaf((float)v[i][e + 4], s1[e], h1[e]));
      }
      const int boff = row * 128 + ((cch * 16) ^ ((row & 7) << 4));
      *reinterpret_cast<bf16x8*>(reinterpret_cast<char*>(AsB + buf * 8192) + boff) = y;
    }
  };

  f32x4 acc[4][4] = {};
  const int fr = lane & 15, kc = lane >> 4;
  auto compute = [&](int buf) {
#pragma unroll
    for (int kk = 0; kk < 2; ++kk) {
      bf16x8 af[4], bfq[4];
#pragma unroll
      for (int mf = 0; mf < 4; ++mf) {
        const int row  = wr * 64 + mf * 16 + fr;
        const int boff = row * 128 + ((kk * 64 + kc * 16) ^ ((row & 7) << 4));
        af[mf] = *reinterpret_cast<const bf16x8*>(
            reinterpret_cast<const char*>(AsB + buf * 8192) + boff);
      }
#pragma unroll
      for (int nf = 0; nf < 4; ++nf) {
        const int row  = wc * 64 + nf * 16 + fr;
        const int boff = row * 128 + ((kk * 64 + kc * 16) ^ ((row & 7) << 4));
        bfq[nf] = *reinterpret_cast<const bf16x8*>(
            reinterpret_cast<const char*>(BsB + buf * 8192) + boff);
      }
#pragma unroll
      for (int mf = 0; mf < 4; ++mf)
#pragma unroll
        for (int nf = 0; nf < 4; ++nf)
          acc[mf][nf] = __builtin_amdgcn_mfma_f32_16x16x32_bf16(af[mf], bfq[nf], acc[mf][nf], 0, 0, 0);
    }
  };

  if (BN_A) {
    bf16x8 v0[4];
    load_a(v0, 0);
    bn_write(v0, 0, 0);
  } else {
    stage_a(0, 0);
  }
  stage_b(0, 0);
  __syncthreads();

  int buf = 0;
  for (int kt = 0; kt < 8; ++kt) {
    bf16x8 vn[4];
    if (kt < 7) {
      stage_b(buf ^ 1, kt + 1);
      if (!BN_A) stage_a(buf ^ 1, kt + 1);
      else       load_a(vn, kt + 1);
    }
    compute(buf);
    if (BN_A && kt < 7) bn_write(vn, buf ^ 1, kt + 1);
    __syncthreads();
    buf ^= 1;
  }

  const int rq = (lane >> 4) * 4;
#pragma unroll
  for (int nf = 0; nf < 4; ++nf) {
    const int oc = n0 + wc * 64 + nf * 16 + fr;
    float s = 0.f, s2 = 0.f;
#pragma unroll
    for (int mf = 0; mf < 4; ++mf) {
      const int rb = m0 + wr * 64 + mf * 16 + rq;
      f32x4 v = acc[mf][nf];
#pragma unroll
      for (int j = 0; j < 4; ++j) {
        const float f = v[j];
        Co[(size_t)(rb + j) * RS_ + (size_t)h * C_ + oc] = (__bf16)f;
        s += f;
        s2 += f * f;
      }
    }
    s  += __shfl_xor(s, 16);  s  += __shfl_xor(s, 32);
    s2 += __shfl_xor(s2, 16); s2 += __shfl_xor(s2, 32);
    if (lane < 16) {
      atomicAdd(&sum_out[oc], s);
      atomicAdd(&sq_out[oc], s2);
    }
  }
}

// ---------------------------------------------------------------------------
// K2: GEMM1 (x^T * w1^T layouts), raw A.
// ---------------------------------------------------------------------------
__global__ __launch_bounds__(256, 2) void k_gemm1(
    const __bf16* __restrict__ xT, const __bf16* __restrict__ w1T,
    __bf16* __restrict__ t1T,
    float* __restrict__ sum1, float* __restrict__ sq1) {
  __shared__ __bf16 As[2][8192];
  __shared__ __bf16 Bs[2][8192];
  gemm_body<false>(xT, w1T, t1T, nullptr, nullptr, nullptr, nullptr,
                   sum1, sq1, (int)blockIdx.x, (int)threadIdx.x,
                   &As[0][0], &Bs[0][0], nullptr, nullptr);
}

// ---------------------------------------------------------------------------
// K3: GEMM2 with fused BN1+ReLU on A.
// ---------------------------------------------------------------------------
__global__ __launch_bounds__(256, 2) void k_gemm2(
    const __bf16* __restrict__ t1T, const __bf16* __restrict__ w2T,
    __bf16* __restrict__ t2T,
    const float* __restrict__ sum1, const float* __restrict__ sq1,
    const float* __restrict__ g1, const float* __restrict__ b1,
    float* __restrict__ sum2, float* __restrict__ sq2) {
  __shared__ __bf16 As[2][8192];
  __shared__ __bf16 Bs[2][8192];
  __shared__ float a_lds[512], c_lds[512];
  gemm_body<true>(t1T, w2T, t2T, sum1, sq1, g1, b1, sum2, sq2,
                  (int)blockIdx.x, (int)threadIdx.x,
                  &As[0][0], &Bs[0][0], a_lds, c_lds);
}

// ---------------------------------------------------------------------------
// K4: out[n][o][h] = relu(a2[o]*t2[n][h][o] + c2[o] + x[n][o][h])
// t2 layout (N, H, C); a2/c2 computed per block from sum2/sq2.
// ---------------------------------------------------------------------------
__global__ __launch_bounds__(256) void k_finalize(const __bf16* __restrict__ t2,
                                                  const float* __restrict__ x,
                                                  const float* __restrict__ sum2,
                                                  const float* __restrict__ sq2,
                                                  const float* __restrict__ g2,
                                                  const float* __restrict__ b2,
                                                  float* __restrict__ out) {
  __shared__ float tile[64][65];
  __shared__ float a2s[64], c2s[64];
  const int n  = blockIdx.y;
  const int o0 = blockIdx.x * 64;
  const int t  = threadIdx.x;
  if (t < 64) {
    const int o = o0 + t;
    const float m    = sum2[o] * (1.f / 16384.f);
    const float var  = fmaxf(0.f, sq2[o] * (1.f / 16384.f) - m * m);
    const float a    = g2[o] * rsqrtf(var + 1e-5f);
    a2s[t] = a;
    c2s[t] = b2[o] - m * a;
  }
  const __bf16* tb = t2 + (size_t)n * RS_ + o0;
#pragma unroll
  for (int j = 0; j < 4; ++j) {
    const int hh = j * 16 + (t >> 4);
    const int ol = (t & 15) * 4;
    const bf16x4 v = *reinterpret_cast<const bf16x4*>(tb + (size_t)hh * 512 + ol);
#pragma unroll
    for (int e = 0; e < 4; ++e) tile[hh][ol + e] = (float)v[e];
  }
  __syncthreads();
  const int ol = t >> 2;
  const int hb = (t & 3) * 16;
  const int o  = o0 + ol;
  const float a = a2s[ol], c = c2s[ol];
  const float4* xp = reinterpret_cast<const float4*>(x + ((size_t)n * C_ + o) * H_ + hb);
  float4* op = reinterpret_cast<float4*>(out + ((size_t)n * C_ + o) * H_ + hb);
#pragma unroll
  for (int i4 = 0; i4 < 4; ++i4) {
    const float4 xv = xp[i4];
    float4 r;
    r.x = fmaxf(0.f, fmaf(a, tile[hb + i4 * 4 + 0][ol], c) + xv.x);
    r.y = fmaxf(0.f, fmaf(a, tile[hb + i4 * 4 + 1][ol], c) + xv.y);
    r.z = fmaxf(0.f, fmaf(a, tile[hb + i4 * 4 + 2][ol], c) + xv.z);
    r.w = fmaxf(0.f, fmaf(a, tile[hb + i4 * 4 + 3][ol], c) + xv.w);
    op[i4] = r;
  }
}

// ---------------------------------------------------------------------------
extern "C" void kernel_launch(void* const* d_in, const int* in_sizes, int n_in,
                              void* d_out, int out_size, void* d_ws, size_t ws_size,
                              hipStream_t stream) {
  const float* x  = (const float*)d_in[0];
  const float* w1 = (const float*)d_in[1];
  const float* g1 = (const float*)d_in[2];
  const float* b1 = (const float*)d_in[3];
  const float* w2 = (const float*)d_in[4];
  const float* g2 = (const float*)d_in[5];
  const float* b2 = (const float*)d_in[6];
  float* out = (float*)d_out;

  char* ws = (char*)d_ws;
  float* stats = (float*)ws;  // sum1, sq1, sum2, sq2
  float* sum1 = stats,        *sq1 = stats + 512;
  float* sum2 = stats + 1024, *sq2 = stats + 1536;
  const size_t MB = (size_t)1 << 20;
  __bf16* xT  = (__bf16*)(ws + 64 * 1024);
  __bf16* w1T = (__bf16*)(ws + 64 * 1024 + 16 * MB);
  __bf16* w2T = (__bf16*)(ws + 64 * 1024 + 48 * MB);
  __bf16* t1T = (__bf16*)(ws + 64 * 1024 + 80 * MB);
  __bf16* t2T = (__bf16*)(ws + 64 * 1024 + 96 * MB);

  k_prep_direct<<<2048, 256, 0, stream>>>(x, w1, w2, xT, w1T, w2T, stats);
  k_gemm1<<<512, 256, 0, stream>>>(xT, w1T, t1T, sum1, sq1);
  k_gemm2<<<512, 256, 0, stream>>>(t1T, w2T, t2T, sum1, sq1, g1, b1, sum2, sq2);
  k_finalize<<<dim3(8, 256), 256, 0, stream>>>(t2T, x, sum2, sq2, g2, b2, out);
}

// Round 13
// 122.986 us; speedup vs baseline: 1.2475x; 1.2475x over previous
//
#include <hip/hip_runtime.h>
#include <stdint.h>

typedef float  f32x4  __attribute__((ext_vector_type(4)));
typedef __bf16 bf16x8 __attribute__((ext_vector_type(8)));
typedef __bf16 bf16x4 __attribute__((ext_vector_type(4)));

#define N_ 256
#define C_ 512
#define H_ 64
#define RS_ 32768  // row stride in transposed tensors: H_*C_ elements

__device__ __forceinline__ uint32_t pack_bf16x2(float a, float b) {
  const uint16_t ua = __builtin_bit_cast(uint16_t, (__bf16)a);
  const uint16_t ub = __builtin_bit_cast(uint16_t, (__bf16)b);
  return (uint32_t)ua | ((uint32_t)ub << 16);
}

// ---------------------------------------------------------------------------
// Async-staged transpose (GEMM-staging rhythm): (P,512c,64h) fp32 ->
// (P,64h,512c) bf16.  Task = (p, 16-h slice); per task:
//   STAGE: 32x global_load_lds dwordx4 (async queue, no VGPR round-trip) --
//     each 4-lane cluster reads one FULL 64B line x[p][c][h0:h0+16]; h-quad
//     order pre-swizzled by K=(c>>3)&12 on the global source (quad-granular
//     keeps 16B contiguity) so LDS [c][slot] reads are 4-way, not 16-way.
//   CONSUME: thread=(hrel=t>>4, cchunk=t&15): 4x{8 ds_read_b32 at constant
//     slot=hrel^(t&12), pack, ONE uint4 store; 16-lane groups store 256B
//     contiguous} -> no partial-line RMW.
// Double-buffered 2x32KB, one barrier per task (same drain the 15TB/s GEMM
// staging eats).  1024 blocks x 5 tasks.  Block 0 zeroes BN stats.
// ---------------------------------------------------------------------------
__global__ __launch_bounds__(256, 2) void k_prep_gl(
    const float* __restrict__ x, const float* __restrict__ w1,
    const float* __restrict__ w2,
    __bf16* __restrict__ xT, __bf16* __restrict__ w1T,
    __bf16* __restrict__ w2T, float* __restrict__ stats) {
  __shared__ float tile[2][8192];   // 2 x 32 KB
  const int t = threadIdx.x, w = t >> 6, l = t & 63;
  if (blockIdx.x == 0) {
#pragma unroll
    for (int i = 0; i < 8; ++i) stats[i * 256 + t] = 0.f;  // sum1,sq1,sum2,sq2
  }
  const int hrel = t >> 4;            // consume: output h within slice
  const int cch  = t & 15;            // consume: c-chunk
  const int slot = hrel ^ (t & 12);   // consume: constant LDS h-slot

  auto sel = [&](int p, const float*& src, __bf16*& dst, int& pp) {
    if (p < 256)      { src = x;  dst = xT;  pp = p; }
    else if (p < 768) { src = w1; dst = w1T; pp = p - 256; }
    else              { src = w2; dst = w2T; pp = p - 768; }
  };

  auto stage = [&](int buf, int task) {
    const int p = task >> 2, h0 = (task & 3) * 16;
    const float* src; __bf16* dst; int pp;
    sel(p, src, dst, pp);
    const float* sp = src + (size_t)pp * 32768 + h0;
    const int csub = l >> 2;
    const int hbase = (l & 3) * 4;
#pragma unroll
    for (int r = 0; r < 8; ++r) {
      const int j = w * 8 + r;                   // 0..31
      const int c = j * 16 + csub;
      const int K = (j * 2 + (l >> 5)) & 12;     // quad swizzle key
      const float* gp = sp + (size_t)c * 64 + (hbase ^ K);
      __builtin_amdgcn_global_load_lds(
          (const __attribute__((address_space(1))) void*)gp,
          (__attribute__((address_space(3))) void*)(&tile[buf][j * 256]),
          16, 0, 0);
    }
  };

  auto consume = [&](int buf, int task) {
    const int p = task >> 2, h0 = (task & 3) * 16;
    const float* src; __bf16* dst; int pp;
    sel(p, src, dst, pp);
    __bf16* drow = dst + (size_t)pp * RS_ + (size_t)(h0 + hrel) * 512;
#pragma unroll
    for (int k = 0; k < 4; ++k) {
      const int cb = k * 128 + cch * 8;
      float v[8];
#pragma unroll
      for (int i = 0; i < 8; ++i)
        v[i] = tile[buf][(cb + i) * 16 + slot];
      uint4 o;
      o.x = pack_bf16x2(v[0], v[1]);
      o.y = pack_bf16x2(v[2], v[3]);
      o.z = pack_bf16x2(v[4], v[5]);
      o.w = pack_bf16x2(v[6], v[7]);
      *reinterpret_cast<uint4*>(drow + cb) = o;
    }
  };

  int task = blockIdx.x;       // 5120 tasks = 1280 p x 4 h-slices
  stage(0, task);
  __syncthreads();
  int buf = 0;
#pragma unroll 1
  for (int it = 0; it < 5; ++it) {
    if (it < 4) stage(buf ^ 1, task + 1024);
    consume(buf, task);
    __syncthreads();
    buf ^= 1;
    task += 1024;
  }
}

// ---------------------------------------------------------------------------
// Batched NT GEMM body: per h, C[256][512] = A[256][512]*B[512][512]^T (bf16)
// Layouts (row stride RS_). 128x128 tile, 4 waves, BK=64, double-buffered
// global_load_lds staging with chunk-XOR swizzle via pre-swizzled source.
// gblk in [0,512): wkid = (gblk&7)*64 + (gblk>>3) colocates same-h on XCD.
// Epilogue: bf16 C + per-channel sum/sumsq atomics.
// BN_A: A gets y = relu(a1[k]*a + c1[k]) from sum_in/sq_in on the fly.
// ---------------------------------------------------------------------------
template <bool BN_A>
__device__ __forceinline__ void gemm_body(
    const __bf16* __restrict__ A, const __bf16* __restrict__ B,
    __bf16* __restrict__ Co,
    const float* __restrict__ sum_in, const float* __restrict__ sq_in,
    const float* __restrict__ g, const float* __restrict__ bb,
    float* __restrict__ sum_out, float* __restrict__ sq_out,
    int gblk, int tid, __bf16* AsB, __bf16* BsB,
    float* a_lds, float* c_lds) {
  const int wkid = (gblk & 7) * 64 + (gblk >> 3);
  const int h  = wkid >> 3;
  const int tm = (wkid >> 2) & 1, tn = wkid & 3;
  const int m0 = tm * 128, n0 = tn * 128;
  const __bf16* Ah = A + (size_t)m0 * RS_ + (size_t)h * C_;
  const __bf16* Bh = B + (size_t)n0 * RS_ + (size_t)h * C_;
  const int lane = tid & 63, wid = tid >> 6;
  const int wr = wid >> 1, wc = wid & 1;
  const int lrow8 = lane >> 3;
  const int swz   = (lane & 7) ^ lrow8;

  if (BN_A) {
#pragma unroll
    for (int ch = tid; ch < 512; ch += 256) {
      const float m    = sum_in[ch] * (1.f / 16384.f);
      const float var  = fmaxf(0.f, sq_in[ch] * (1.f / 16384.f) - m * m);
      const float aa   = g[ch] * rsqrtf(var + 1e-5f);
      a_lds[ch] = aa;
      c_lds[ch] = bb[ch] - m * aa;
    }
    __syncthreads();
  }

  auto stage_b = [&](int buf, int kt) {
#pragma unroll
    for (int i = 0; i < 4; ++i) {
      const int rbase = wid * 32 + i * 8;
      const __bf16* gb = Bh + (size_t)(rbase + lrow8) * RS_ + kt * 64 + swz * 8;
      __builtin_amdgcn_global_load_lds(
          (const __attribute__((address_space(1))) void*)gb,
          (__attribute__((address_space(3))) void*)(BsB + buf * 8192 + rbase * 64),
          16, 0, 0);
    }
  };
  auto stage_a = [&](int buf, int kt) {
#pragma unroll
    for (int i = 0; i < 4; ++i) {
      const int rbase = wid * 32 + i * 8;
      const __bf16* ga = Ah + (size_t)(rbase + lrow8) * RS_ + kt * 64 + swz * 8;
      __builtin_amdgcn_global_load_lds(
          (const __attribute__((address_space(1))) void*)ga,
          (__attribute__((address_space(3))) void*)(AsB + buf * 8192 + rbase * 64),
          16, 0, 0);
    }
  };
  const int lr32 = tid >> 3, cch = tid & 7;
  auto load_a = [&](bf16x8* v, int kt) {
#pragma unroll
    for (int i = 0; i < 4; ++i)
      v[i] = *reinterpret_cast<const bf16x8*>(
          Ah + (size_t)(i * 32 + lr32) * RS_ + kt * 64 + cch * 8);
  };
  auto bn_write = [&](const bf16x8* v, int buf, int kt) {
    const int cg = kt * 64 + cch * 8;
    const f32x4 s0 = *reinterpret_cast<const f32x4*>(&a_lds[cg]);
    const f32x4 s1 = *reinterpret_cast<const f32x4*>(&a_lds[cg + 4]);
    const f32x4 h0 = *reinterpret_cast<const f32x4*>(&c_lds[cg]);
    const f32x4 h1 = *reinterpret_cast<const f32x4*>(&c_lds[cg + 4]);
#pragma unroll
    for (int i = 0; i < 4; ++i) {
      const int row = i * 32 + lr32;
      bf16x8 y;
#pragma unroll
      for (int e = 0; e < 4; ++e) {
        y[e]     = (__bf16)fmaxf(0.f, fmaf((float)v[i][e],     s0[e], h0[e]));
        y[e + 4] = (__bf16)fmaxf(0.f, fmaf((float)v[i][e + 4], s1[e], h1[e]));
      }
      const int boff = row * 128 + ((cch * 16) ^ ((row & 7) << 4));
      *reinterpret_cast<bf16x8*>(reinterpret_cast<char*>(AsB + buf * 8192) + boff) = y;
    }
  };

  f32x4 acc[4][4] = {};
  const int fr = lane & 15, kc = lane >> 4;
  auto compute = [&](int buf) {
#pragma unroll
    for (int kk = 0; kk < 2; ++kk) {
      bf16x8 af[4], bfq[4];
#pragma unroll
      for (int mf = 0; mf < 4; ++mf) {
        const int row  = wr * 64 + mf * 16 + fr;
        const int boff = row * 128 + ((kk * 64 + kc * 16) ^ ((row & 7) << 4));
        af[mf] = *reinterpret_cast<const bf16x8*>(
            reinterpret_cast<const char*>(AsB + buf * 8192) + boff);
      }
#pragma unroll
      for (int nf = 0; nf < 4; ++nf) {
        const int row  = wc * 64 + nf * 16 + fr;
        const int boff = row * 128 + ((kk * 64 + kc * 16) ^ ((row & 7) << 4));
        bfq[nf] = *reinterpret_cast<const bf16x8*>(
            reinterpret_cast<const char*>(BsB + buf * 8192) + boff);
      }
#pragma unroll
      for (int mf = 0; mf < 4; ++mf)
#pragma unroll
        for (int nf = 0; nf < 4; ++nf)
          acc[mf][nf] = __builtin_amdgcn_mfma_f32_16x16x32_bf16(af[mf], bfq[nf], acc[mf][nf], 0, 0, 0);
    }
  };

  if (BN_A) {
    bf16x8 v0[4];
    load_a(v0, 0);
    bn_write(v0, 0, 0);
  } else {
    stage_a(0, 0);
  }
  stage_b(0, 0);
  __syncthreads();

  int buf = 0;
  for (int kt = 0; kt < 8; ++kt) {
    bf16x8 vn[4];
    if (kt < 7) {
      stage_b(buf ^ 1, kt + 1);
      if (!BN_A) stage_a(buf ^ 1, kt + 1);
      else       load_a(vn, kt + 1);
    }
    compute(buf);
    if (BN_A && kt < 7) bn_write(vn, buf ^ 1, kt + 1);
    __syncthreads();
    buf ^= 1;
  }

  const int rq = (lane >> 4) * 4;
#pragma unroll
  for (int nf = 0; nf < 4; ++nf) {
    const int oc = n0 + wc * 64 + nf * 16 + fr;
    float s = 0.f, s2 = 0.f;
#pragma unroll
    for (int mf = 0; mf < 4; ++mf) {
      const int rb = m0 + wr * 64 + mf * 16 + rq;
      f32x4 v = acc[mf][nf];
#pragma unroll
      for (int j = 0; j < 4; ++j) {
        const float f = v[j];
        Co[(size_t)(rb + j) * RS_ + (size_t)h * C_ + oc] = (__bf16)f;
        s += f;
        s2 += f * f;
      }
    }
    s  += __shfl_xor(s, 16);  s  += __shfl_xor(s, 32);
    s2 += __shfl_xor(s2, 16); s2 += __shfl_xor(s2, 32);
    if (lane < 16) {
      atomicAdd(&sum_out[oc], s);
      atomicAdd(&sq_out[oc], s2);
    }
  }
}

// ---------------------------------------------------------------------------
// K2: GEMM1 (x^T * w1^T layouts), raw A.
// ---------------------------------------------------------------------------
__global__ __launch_bounds__(256, 2) void k_gemm1(
    const __bf16* __restrict__ xT, const __bf16* __restrict__ w1T,
    __bf16* __restrict__ t1T,
    float* __restrict__ sum1, float* __restrict__ sq1) {
  __shared__ __bf16 As[2][8192];
  __shared__ __bf16 Bs[2][8192];
  gemm_body<false>(xT, w1T, t1T, nullptr, nullptr, nullptr, nullptr,
                   sum1, sq1, (int)blockIdx.x, (int)threadIdx.x,
                   &As[0][0], &Bs[0][0], nullptr, nullptr);
}

// ---------------------------------------------------------------------------
// K3: GEMM2 with fused BN1+ReLU on A.
// ---------------------------------------------------------------------------
__global__ __launch_bounds__(256, 2) void k_gemm2(
    const __bf16* __restrict__ t1T, const __bf16* __restrict__ w2T,
    __bf16* __restrict__ t2T,
    const float* __restrict__ sum1, const float* __restrict__ sq1,
    const float* __restrict__ g1, const float* __restrict__ b1,
    float* __restrict__ sum2, float* __restrict__ sq2) {
  __shared__ __bf16 As[2][8192];
  __shared__ __bf16 Bs[2][8192];
  __shared__ float a_lds[512], c_lds[512];
  gemm_body<true>(t1T, w2T, t2T, sum1, sq1, g1, b1, sum2, sq2,
                  (int)blockIdx.x, (int)threadIdx.x,
                  &As[0][0], &Bs[0][0], a_lds, c_lds);
}

// ---------------------------------------------------------------------------
// K4: out[n][o][h] = relu(a2[o]*t2[n][h][o] + c2[o] + x[n][o][h])
// t2 layout (N, H, C); a2/c2 computed per block from sum2/sq2.
// ---------------------------------------------------------------------------
__global__ __launch_bounds__(256) void k_finalize(const __bf16* __restrict__ t2,
                                                  const float* __restrict__ x,
                                                  const float* __restrict__ sum2,
                                                  const float* __restrict__ sq2,
                                                  const float* __restrict__ g2,
                                                  const float* __restrict__ b2,
                                                  float* __restrict__ out) {
  __shared__ float tile[64][65];
  __shared__ float a2s[64], c2s[64];
  const int n  = blockIdx.y;
  const int o0 = blockIdx.x * 64;
  const int t  = threadIdx.x;
  if (t < 64) {
    const int o = o0 + t;
    const float m    = sum2[o] * (1.f / 16384.f);
    const float var  = fmaxf(0.f, sq2[o] * (1.f / 16384.f) - m * m);
    const float a    = g2[o] * rsqrtf(var + 1e-5f);
    a2s[t] = a;
    c2s[t] = b2[o] - m * a;
  }
  const __bf16* tb = t2 + (size_t)n * RS_ + o0;
#pragma unroll
  for (int j = 0; j < 4; ++j) {
    const int hh = j * 16 + (t >> 4);
    const int ol = (t & 15) * 4;
    const bf16x4 v = *reinterpret_cast<const bf16x4*>(tb + (size_t)hh * 512 + ol);
#pragma unroll
    for (int e = 0; e < 4; ++e) tile[hh][ol + e] = (float)v[e];
  }
  __syncthreads();
  const int ol = t >> 2;
  const int hb = (t & 3) * 16;
  const int o  = o0 + ol;
  const float a = a2s[ol], c = c2s[ol];
  const float4* xp = reinterpret_cast<const float4*>(x + ((size_t)n * C_ + o) * H_ + hb);
  float4* op = reinterpret_cast<float4*>(out + ((size_t)n * C_ + o) * H_ + hb);
#pragma unroll
  for (int i4 = 0; i4 < 4; ++i4) {
    const float4 xv = xp[i4];
    float4 r;
    r.x = fmaxf(0.f, fmaf(a, tile[hb + i4 * 4 + 0][ol], c) + xv.x);
    r.y = fmaxf(0.f, fmaf(a, tile[hb + i4 * 4 + 1][ol], c) + xv.y);
    r.z = fmaxf(0.f, fmaf(a, tile[hb + i4 * 4 + 2][ol], c) + xv.z);
    r.w = fmaxf(0.f, fmaf(a, tile[hb + i4 * 4 + 3][ol], c) + xv.w);
    op[i4] = r;
  }
}

// ---------------------------------------------------------------------------
extern "C" void kernel_launch(void* const* d_in, const int* in_sizes, int n_in,
                              void* d_out, int out_size, void* d_ws, size_t ws_size,
                              hipStream_t stream) {
  const float* x  = (const float*)d_in[0];
  const float* w1 = (const float*)d_in[1];
  const float* g1 = (const float*)d_in[2];
  const float* b1 = (const float*)d_in[3];
  const float* w2 = (const float*)d_in[4];
  const float* g2 = (const float*)d_in[5];
  const float* b2 = (const float*)d_in[6];
  float* out = (float*)d_out;

  char* ws = (char*)d_ws;
  float* stats = (float*)ws;  // sum1, sq1, sum2, sq2
  float* sum1 = stats,        *sq1 = stats + 512;
  float* sum2 = stats + 1024, *sq2 = stats + 1536;
  const size_t MB = (size_t)1 << 20;
  __bf16* xT  = (__bf16*)(ws + 64 * 1024);
  __bf16* w1T = (__bf16*)(ws + 64 * 1024 + 16 * MB);
  __bf16* w2T = (__bf16*)(ws + 64 * 1024 + 48 * MB);
  __bf16* t1T = (__bf16*)(ws + 64 * 1024 + 80 * MB);
  __bf16* t2T = (__bf16*)(ws + 64 * 1024 + 96 * MB);

  k_prep_gl<<<1024, 256, 0, stream>>>(x, w1, w2, xT, w1T, w2T, stats);
  k_gemm1<<<512, 256, 0, stream>>>(xT, w1T, t1T, sum1, sq1);
  k_gemm2<<<512, 256, 0, stream>>>(t1T, w2T, t2T, sum1, sq1, g1, b1, sum2, sq2);
  k_finalize<<<dim3(8, 256), 256, 0, stream>>>(t2T, x, sum2, sq2, g2, b2, out);
}